// Round 19
// baseline (180.192 us; speedup 1.0000x reference)
//
#include <hip/hip_runtime.h>
#include <hip/hip_bf16.h>
#include <hip/hip_fp8.h>
#include <math.h>

#define M_HALF 2097152          // 2^21, half-length complex IFFT size
#define W_SCALE 256.0f          // w folded scale (w ~ 2.4e-4 is below e4m3 subnormals)

typedef __bf16 bf16_t;
typedef unsigned char u8;
typedef __attribute__((ext_vector_type(4))) float f32x4;
typedef __attribute__((ext_vector_type(4))) int   i32x4;
typedef __attribute__((ext_vector_type(8))) int   i32x8;

#define GLOBAL_AS __attribute__((address_space(1)))
#define LDS_AS    __attribute__((address_space(3)))

__device__ __forceinline__ u8 to_fp8(float v) {
    __hip_fp8_e4m3 t(v);
    return *reinterpret_cast<u8*>(&t);
}

__device__ __forceinline__ float2 cadd(float2 a, float2 b){ return make_float2(a.x+b.x, a.y+b.y); }
__device__ __forceinline__ float2 csub(float2 a, float2 b){ return make_float2(a.x-b.x, a.y-b.y); }
__device__ __forceinline__ float2 cmul(float2 a, float2 b){ return make_float2(a.x*b.x-a.y*b.y, a.x*b.y+a.y*b.x); }
__device__ __forceinline__ float2 cmuli(float2 a){ return make_float2(-a.y, a.x); } // *(+i)

// inverse 8-point DFT (positive exponent), natural order
__device__ __forceinline__ void radix8_inv(const float2 v[8], float2 X[8]) {
    const float cc = 0.70710678118654752f;
    float2 a0 = cadd(v[0], v[4]), a1 = cadd(v[1], v[5]), a2 = cadd(v[2], v[6]), a3 = cadd(v[3], v[7]);
    float2 b0 = csub(v[0], v[4]), b1 = csub(v[1], v[5]), b2 = csub(v[2], v[6]), b3 = csub(v[3], v[7]);
    b1 = cmul(b1, make_float2(cc, cc));
    b2 = cmuli(b2);
    b3 = cmul(b3, make_float2(-cc, cc));
    float2 c0 = cadd(a0, a2), c1 = cadd(a1, a3), d0 = csub(a0, a2), d1 = cmuli(csub(a1, a3));
    float2 e0 = cadd(b0, b2), e1 = cadd(b1, b3), f0 = csub(b0, b2), f1 = cmuli(csub(b1, b3));
    X[0] = cadd(c0, c1); X[4] = csub(c0, c1); X[2] = cadd(d0, d1); X[6] = csub(d0, d1);
    X[1] = cadd(e0, e1); X[5] = csub(e0, e1); X[3] = cadd(f0, f1); X[7] = csub(f0, f1);
}

// ---------------- zero / scatter (transposed spectrum layout) ----------------

__global__ __launch_bounds__(256) void zero2_kernel(float2* p, int n) {
    int i = blockIdx.x*256 + threadIdx.x;
    if (i < n) p[i] = make_float2(0.f, 0.f);
}

__global__ __launch_bounds__(256) void scatter2_kernel(const float* __restrict__ crA,
                                                       const float* __restrict__ ciA,
                                                       const int* __restrict__ idxA,
                                                       const float* __restrict__ crB,
                                                       const float* __restrict__ ciB,
                                                       const int* __restrict__ idxB,
                                                       float2* __restrict__ specA,
                                                       float2* __restrict__ specB, int keep) {
    int i = blockIdx.x*256 + threadIdx.x;
    if (i < keep) {
        int k = idxA[i];
        long pos = (k < M_HALF) ? ((long)(k & 511)*4096 + (k >> 9)) : (long)M_HALF;
        specA[pos] = make_float2(crA[i], ciA[i]);
    } else if (i < 2*keep) {
        int t = i - keep;
        int k = idxB[t];
        long pos = (k < M_HALF) ? ((long)(k & 511)*4096 + (k >> 9)) : (long)M_HALF;
        specB[pos] = make_float2(crB[t], ciB[t]);
    }
}

// ---------------- pass 1: radix-4096 in-block (8 x 512-sub), prep fused -----

__global__ __launch_bounds__(512) void ifft_p4096_dual(const float2* __restrict__ specTA,
                                                       const float2* __restrict__ specTB,
                                                       float2* __restrict__ dstA,
                                                       float2* __restrict__ dstB,
                                                       const float* __restrict__ scaleA,
                                                       const float* __restrict__ scaleB) {
    __shared__ float2 L[8*656];
    int bb = blockIdx.x;
    const float2* spec; float2* dst; const float* scale;
    if (bb < 512) { spec = specTA; dst = dstA; scale = scaleA; }
    else          { bb -= 512; spec = specTB; dst = dstB; scale = scaleB; }
    const int j = bb;
    const int x = threadIdx.x;       // [0,512)
    const float s = scale[0] * (1.0f/(float)M_HALF);
    float2 v[8];
    {   // prep: angle pi*k/2^21, k = j + 512*(x+512u); step over u = pi/8
        float ang0 = (float)(3.14159265358979323846 * (double)(j + 512*x) / 2097152.0);
        float sn, cs; sincosf(ang0, &sn, &cs);
        const float2 step = make_float2(0.98078528040323044913f,
                                        0.19509032201612826785f);
        float2 tw = make_float2(cs, sn);
        const long arow = (long)j * 4096;
        const long brow = (long)(512 - j) * 4096;
#pragma unroll
        for (int u = 0; u < 8; ++u) {
            int t = x + 512*u;
            float2 a = spec[arow + t];
            float2 b;
            if (j == 0) b = (t == 0) ? spec[(long)M_HALF] : spec[4096 - t];
            else        b = spec[brow + 4095 - t];
            if (j == 0 && t == 0) { a.y = 0.0f; b.y = 0.0f; }
            float Er = 0.5f*(a.x + b.x), Ei = 0.5f*(a.y - b.y);
            float Tr = 0.5f*(a.x - b.x), Ti = 0.5f*(a.y + b.y);
            float Or = Tr*tw.x - Ti*tw.y, Oi = Tr*tw.y + Ti*tw.x;
            v[u] = make_float2((Er - Oi)*s, (Ei + Or)*s);
            tw = cmul(tw, step);
        }
    }
    float2 E[8];
    radix8_inv(v, E);
    {   // twiddle cis(2pi a x / 4096)
        float cb, sb; sincosf((float)x * 0.0015339807878856412f, &sb, &cb);
        float2 wb = make_float2(cb, sb), w = make_float2(1.f, 0.f);
#pragma unroll
        for (int a = 0; a < 8; ++a) { L[a*656 + x] = cmul(E[a], w); w = cmul(w, wb); }
    }
    __syncthreads();
    const int g = x >> 6, xin = x & 63;
    float2* Lg = L + g*656;
    float2 v2[8];
#pragma unroll
    for (int u2 = 0; u2 < 8; ++u2) v2[u2] = Lg[xin + 64*u2];
    float2 E2[8];
    radix8_inv(v2, E2);
    __syncthreads();
    {   // T1 = cis(2pi s8 xin/512)
        float cb, sb; sincosf((float)xin * 0.012271846303085130f, &sb, &cb);
        float2 wb = make_float2(cb, sb), w = make_float2(1.f, 0.f);
#pragma unroll
        for (int s8 = 0; s8 < 8; ++s8) { Lg[s8*65 + xin] = cmul(E2[s8], w); w = cmul(w, wb); }
    }
    __syncthreads();
    const int p = xin >> 3, xa = xin & 7;
    float2 g2[8];
#pragma unroll
    for (int xb = 0; xb < 8; ++xb) g2[xb] = Lg[p*65 + xa + 8*xb];
    float2 H2[8];
    radix8_inv(g2, H2);
    __syncthreads();
    {   // T2 = cis(2pi o8 xa/64)
        float cb, sb; sincosf((float)xa * 0.098174770424681039f, &sb, &cb);
        float2 wb = make_float2(cb, sb), w = make_float2(1.f, 0.f);
#pragma unroll
        for (int o8 = 0; o8 < 8; ++o8) { Lg[p*81 + o8*9 + xa] = cmul(H2[o8], w); w = cmul(w, wb); }
    }
    __syncthreads();
    const int pp = xin & 7, sp = xin >> 3;
    float2 r2[8];
#pragma unroll
    for (int xa2 = 0; xa2 < 8; ++xa2) r2[xa2] = Lg[pp*81 + sp*9 + xa2];
    float2 D[8];
    radix8_inv(r2, D);               // s = g + 8*xin + 512*ob
    __syncthreads();
#pragma unroll
    for (int ob = 0; ob < 8; ++ob) {
        int sg = g + 8*xin + 512*ob;
        L[sg ^ ((sg >> 4) & 7)] = D[ob];
    }
    __syncthreads();
    const long obase = (long)j * 4096;
#pragma unroll
    for (int e = 0; e < 8; ++e) {
        int idx = x + 512*e;
        dst[obase + idx] = L[idx ^ ((idx >> 4) & 7)];
    }
}

// ---------------- pass 2 (FINAL): radix-512, outer twiddle, fp8(x256) out ---
// Natural layout: n = jg + s*4096 complex pairs -> u16 packed fp8 (Re,Im).

__global__ __launch_bounds__(512) void ifft_p512f8_dual(const float2* __restrict__ srcA,
                                                        u8* __restrict__ dstwA,
                                                        const float2* __restrict__ srcB,
                                                        u8* __restrict__ dstwB) {
    __shared__ float2 ex[8 * 642];
    int bb = blockIdx.x;
    const float2* src; u8* dstw;
    if (bb < 512) { src = srcA; dstw = dstwA; }
    else          { bb -= 512; src = srcB; dstw = dstwB; }
    const int tid = threadIdx.x;
    const int jl = tid & 7, x = tid >> 3;    // x in [0,64)
    const int jg = bb * 8 + jl;              // [0,4096)
    float2* W = ex + jl * 642;
    float2 v[8];
    {   // outer twiddle cis(2pi jg (x+64u)/2^21)
        float a0 = (float)(6.283185307179586 * (double)jg * (double)x / 2097152.0);
        float sn0, cs0; sincosf(a0, &sn0, &cs0);
        float as = (float)(6.283185307179586 * (double)jg / 32768.0);
        float sns, css; sincosf(as, &sns, &css);
        float2 tw = make_float2(cs0, sn0), stepw = make_float2(css, sns);
#pragma unroll
        for (int u = 0; u < 8; ++u) {
            v[u] = cmul(src[jg + (long)(x + 64*u) * 4096], tw);
            tw = cmul(tw, stepw);
        }
    }
    float2 E[8];
    radix8_inv(v, E);
    {   // T1 = cis(2pi s8 x / 512)
        float cb, sb; sincosf((float)x * 0.012271846303085130f, &sb, &cb);
        float2 wb = make_float2(cb, sb), w = make_float2(1.f, 0.f);
#pragma unroll
        for (int s8 = 0; s8 < 8; ++s8) {
            W[s8*65 + x] = cmul(E[s8], w);
            w = cmul(w, wb);
        }
    }
    __syncthreads();
    const int p = x >> 3, xa = x & 7;
    float2 g[8];
#pragma unroll
    for (int xb = 0; xb < 8; ++xb) g[xb] = W[p*65 + xa + 8*xb];
    float2 H[8];
    radix8_inv(g, H);
    __syncthreads();
    {   // T2 = cis(2pi o8 xa / 64)
        float cb, sb; sincosf((float)xa * 0.098174770424681039f, &sb, &cb);
        float2 wb = make_float2(cb, sb), w = make_float2(1.f, 0.f);
#pragma unroll
        for (int o8 = 0; o8 < 8; ++o8) {
            W[p*81 + o8*9 + xa] = cmul(H[o8], w);
            w = cmul(w, wb);
        }
    }
    __syncthreads();
    const int pp = x & 7, sp = x >> 3;
    float2 r[8];
#pragma unroll
    for (int xa2 = 0; xa2 < 8; ++xa2) r[xa2] = W[pp*81 + sp*9 + xa2];
    float2 Y[8];
    radix8_inv(r, Y);                // s = x + 64*ob
#pragma unroll
    for (int ob = 0; ob < 8; ++ob) {
        long n = jg + (long)(x + 64*ob) * 4096;
        unsigned short pk = (unsigned short)to_fp8(Y[ob].x * W_SCALE) |
                            ((unsigned short)to_fp8(Y[ob].y * W_SCALE) << 8);
        ((unsigned short*)dstw)[n] = pk;
    }
}

// ---------------- transpose fp8, dual-weight (w[R][C] -> wT[C][R]) ----------

__global__ __launch_bounds__(256) void transpose_f8_dual(const u8* __restrict__ wA,
                                                         u8* __restrict__ wTA,
                                                         const u8* __restrict__ wB,
                                                         u8* __restrict__ wTB) {
    __shared__ u8 tile[32][36];
    int b = blockIdx.x;
    const u8* w; u8* wT; int R, C, bx, by;
    if (b < 4096) { w = wA; wT = wTA; R = 1024; C = 4096; bx = b & 127; by = b >> 7; }
    else { b -= 4096; w = wB; wT = wTB; R = 4096; C = 1024; bx = b & 31; by = b >> 5; }
    int tx = threadIdx.x & 31, ty = threadIdx.x >> 5;
    long c0 = (long)bx * 32, r0 = (long)by * 32;
#pragma unroll
    for (int i = 0; i < 4; ++i)
        tile[ty + i*8][tx] = w[(r0 + ty + i*8) * C + c0 + tx];
    __syncthreads();
#pragma unroll
    for (int i = 0; i < 4; ++i) {
        int c = ty + i*8;
        wT[(c0 + c) * R + r0 + tx] = tile[tx][c];
    }
}

// ---------------- fp32 -> fp8 convert (x), natural layout ----------------

__global__ __launch_bounds__(256) void cvt_fp8_kernel(const float* __restrict__ in,
                                                      u8* __restrict__ out, int n4) {
    int i = blockIdx.x*256 + threadIdx.x;
    if (i < n4) {
        float4 v = ((const float4*)in)[i];
        unsigned int pk = (unsigned int)to_fp8(v.x) |
                          ((unsigned int)to_fp8(v.y) << 8) |
                          ((unsigned int)to_fp8(v.z) << 16) |
                          ((unsigned int)to_fp8(v.w) << 24);
        ((unsigned int*)out)[i] = pk;
    }
}

// ---------------- staging helper (byte-based, swizzled) ----------------
// LDS[row][gb] = G[row][gb ^ (row&7)] on 16B granules within 128B rows:
// pre-swizzled global source -> linear global_load_lds dest; reads XOR back.

template<int NITER>
__device__ __forceinline__ void stage_b(const u8* g, int ldB, int row0, int col0B,
                                        u8* lds, int tid) {
    int w = tid >> 6, l = tid & 63;        // w in [0,8)
    int r8 = l >> 3;
    int cg = ((l & 7) ^ r8) << 4;          // pre-swizzled byte col (16B granule)
#pragma unroll
    for (int i = 0; i < NITER; ++i) {
        int chunk = (i << 3) + w;          // NITER*8 chunks x 8 rows x 128 B
        const u8* ga = g + (long)(row0 + chunk*8 + r8) * ldB + col0B + cg;
        u8* la = lds + (chunk << 10);
        __builtin_amdgcn_global_load_lds((const GLOBAL_AS unsigned int*)ga,
                                         (LDS_AS unsigned int*)la, 16, 0, 0);
    }
}

// 32B fragment load as TWO UNMERGEABLE ds_read_b128.
// The empty asm pins the byte offsets as opaque VGPR values so the compiler
// cannot prove the two 16B loads adjacent and re-lower them as 4x ds_read_b64
// (sub-16B reads under the 16B-granule XOR swizzle = the r16/r17 4-way
// conflict; r18's 6.29e6 conflict count matches that lowering).
__device__ __forceinline__ i32x8 ld_frag32(const u8* base, unsigned o0, unsigned o1) {
    asm volatile("" : "+v"(o0), "+v"(o1));
    i32x4 lo = *(const i32x4*)(base + o0);
    i32x4 hi = *(const i32x4*)(base + o1);
    return __builtin_shufflevector(lo, hi, 0, 1, 2, 3, 4, 5, 6, 7);
}

// ---------------- 128x128-tile GEMM, 8 waves, MX-scaled fp8 K=128 ------------
// One v_mfma_scale_f32_16x16x128_f8f6f4 (2x non-scaled fp8 rate) per (mi,ni)
// per K-tile; e8m0 scales = 1.0 (0x7F) -> numerically identical to plain fp8.
// Per-lane fragment k = (l>>4)*32 + j: two XOR'd 16B ds_read_b128 (pinned
// separate -> conflict-free). EPI=0: bias+gelu -> fp8 h ; EPI=1: bias -> fp32.

template<int EPI>
__global__ __launch_bounds__(512, 6) void gemm_f8(const u8* __restrict__ A,
                                                  const u8* __restrict__ Bt,
                                                  const float* __restrict__ bias,
                                                  void* __restrict__ Cout,
                                                  int M, int N, int K,
                                                  int CR, int CC, int GXC) {
    __shared__ __align__(16) u8 lA[128*128];
    __shared__ __align__(16) u8 lB[128*128];
    const int tid = threadIdx.x;
    const int l = tid & 63, w = tid >> 6;
    const int wr = w >> 2, wc = w & 3;
    // XCD-chunked swizzle (bijective; grid multiple of 8)
    int flat = blockIdx.y * gridDim.x + blockIdx.x;
    int r = flat & 7, q = flat >> 3;
    int ty = (r / GXC) * CR + q / CC;
    int tx = (r % GXC) * CC + q % CC;
    const int row0 = ty * 128, col0 = tx * 128;
    const int lr = l & 15, lq = l >> 4;
    const int xr = (lr & 7) << 4;
    const unsigned kb0 = (unsigned)((lq*32) ^ xr);       // two 16B granules
    const unsigned kb1 = (unsigned)((lq*32 + 16) ^ xr);  // = 32 contiguous k
    f32x4 acc[4][2] = {};
    for (int k0 = 0; k0 < K; k0 += 128) {
        stage_b<2>(A,  K, row0, k0, lA, tid);
        stage_b<2>(Bt, K, col0, k0, lB, tid);
        __syncthreads();
        i32x8 bfr[2];
#pragma unroll
        for (int ni = 0; ni < 2; ++ni) {
            unsigned rb = (unsigned)((wc*32 + ni*16 + lr)*128);
            bfr[ni] = ld_frag32(lB, rb + kb0, rb + kb1);
        }
#pragma unroll
        for (int mh = 0; mh < 2; ++mh) {   // mi in {2mh, 2mh+1}: bounds live regs
            i32x8 af[2];
#pragma unroll
            for (int m2 = 0; m2 < 2; ++m2) {
                unsigned ra = (unsigned)((wr*64 + (mh*2 + m2)*16 + lr)*128);
                af[m2] = ld_frag32(lA, ra + kb0, ra + kb1);
            }
#pragma unroll
            for (int m2 = 0; m2 < 2; ++m2)
#pragma unroll
                for (int ni = 0; ni < 2; ++ni)
                    acc[mh*2 + m2][ni] = __builtin_amdgcn_mfma_scale_f32_16x16x128_f8f6f4(
                        af[m2], bfr[ni], acc[mh*2 + m2][ni],
                        0, 0,                      // cbsz=fp8, blgp=fp8
                        0, 0x7F7F7F7F,             // scale_a opsel, e8m0 1.0
                        0, 0x7F7F7F7F);            // scale_b opsel, e8m0 1.0
        }
        __syncthreads();
    }
    const float inv_s = 1.0f / W_SCALE;
#pragma unroll
    for (int mi = 0; mi < 4; ++mi) {
#pragma unroll
        for (int ni = 0; ni < 2; ++ni) {
            int c = col0 + wc*32 + ni*16 + lr;
            float bv = bias[c];
#pragma unroll
            for (int q2 = 0; q2 < 4; ++q2) {
                int rr = row0 + wr*64 + mi*16 + lq*4 + q2;
                float v = acc[mi][ni][q2] * inv_s + bv;
                if constexpr (EPI == 0) {
                    float y = -1.5957691216057308f * (v + 0.044715f * v * v * v);
                    v = v / (1.0f + __expf(y));
                    ((u8*)Cout)[(long)rr * N + c] = to_fp8(v);
                } else {
                    ((float*)Cout)[(long)rr * N + c] = v;
                }
            }
        }
    }
}

// ---------------- launch ----------------

extern "C" void kernel_launch(void* const* d_in, const int* in_sizes, int n_in,
                              void* d_out, int out_size, void* d_ws, size_t ws_size,
                              hipStream_t stream) {
    const float* x        = (const float*)d_in[0];
    const float* fc_cr    = (const float*)d_in[1];
    const float* fc_ci    = (const float*)d_in[2];
    const int*   fc_idx   = (const int*)  d_in[3];
    const float* fc_scale = (const float*)d_in[4];
    const float* fc_bias  = (const float*)d_in[5];
    const float* pj_cr    = (const float*)d_in[6];
    const float* pj_ci    = (const float*)d_in[7];
    const int*   pj_idx   = (const int*)  d_in[8];
    const float* pj_scale = (const float*)d_in[9];
    const float* pj_bias  = (const float*)d_in[10];
    const int keep = in_sizes[1];

    char* ws = (char*)d_ws;
    // Persistent: wT fp8 [0,8), x fp8 [8,16), h fp8 [16,48)
    u8* w_fcT = (u8*)(ws + 0);                  // 4 MiB [4096][1024]
    u8* w_pjT = (u8*)(ws + 4194304);            // 4 MiB [1024][4096]
    u8* x_f8  = (u8*)(ws + 8388608);            // 8 MiB [8192][1024] (written after FFT)
    u8* h_f8  = (u8*)(ws + 16777216);           // 32 MiB [8192][4096] (GEMM1 out)
    // FFT scratch, time-sliced:
    const long SP = (long)M_HALF + 64;
    float2* specA = (float2*)(ws + 8388608);    // [8, ~42): dies after p4096
    float2* specB = specA + SP;
    float2* fftA_A = (float2*)(ws + 50331648);  // [48,64): dies after p512f8
    float2* fftA_B = (float2*)(ws + 67108864);  // [64,80)
    u8* w_natA = (u8*)(ws + 8388608);           // [8,12) over dead spec
    u8* w_natB = (u8*)(ws + 12582912);          // [12,16)

    // --- FFT chain, 2 passes, both weights batched ---
    zero2_kernel<<<(int)((2*SP + 255)/256), 256, 0, stream>>>(specA, (int)(2*SP));
    scatter2_kernel<<<(2*keep + 255)/256, 256, 0, stream>>>(
        fc_cr, fc_ci, fc_idx, pj_cr, pj_ci, pj_idx, specA, specB, keep);
    ifft_p4096_dual<<<1024, 512, 0, stream>>>(specA, specB, fftA_A, fftA_B,
                                              fc_scale, pj_scale);
    ifft_p512f8_dual<<<1024, 512, 0, stream>>>(fftA_A, w_natA, fftA_B, w_natB);
    transpose_f8_dual<<<8192, 256, 0, stream>>>(w_natA, w_fcT, w_natB, w_pjT);

    // --- x -> fp8 (clobbers dead w_nat region, after transpose) ---
    cvt_fp8_kernel<<<8388608/4/256, 256, 0, stream>>>(x, x_f8, 8388608/4);

    // GEMM1: 128^2 tiles, grid = 32 x 64 = 2048; XCD chunks 16x16 (GXC=2)
    gemm_f8<0><<<dim3(4096/128, 8192/128), 512, 0, stream>>>(
        x_f8, w_fcT, fc_bias, h_f8, 8192, 4096, 1024, 16, 16, 2);

    // GEMM2: 128^2 tiles, grid = 8 x 64 = 512; XCD chunks 8x8 (GXC=1)
    gemm_f8<1><<<dim3(1024/128, 8192/128), 512, 0, stream>>>(
        h_f8, w_pjT, pj_bias, d_out, 8192, 1024, 4096, 8, 8, 1);

    (void)n_in; (void)out_size; (void)ws_size;
}

// Round 20
// 170.268 us; speedup vs baseline: 1.0583x; 1.0583x over previous
//
#include <hip/hip_runtime.h>
#include <hip/hip_bf16.h>
#include <hip/hip_fp8.h>
#include <math.h>

#define M_HALF 2097152          // 2^21, half-length complex IFFT size
#define W_SCALE 256.0f          // w folded scale (w ~ 2.4e-4 is below e4m3 subnormals)

typedef __bf16 bf16_t;
typedef unsigned char u8;
typedef __attribute__((ext_vector_type(4))) float f32x4;
typedef __attribute__((ext_vector_type(4))) int   i32x4;
typedef __attribute__((ext_vector_type(8))) int   i32x8;

#define GLOBAL_AS __attribute__((address_space(1)))
#define LDS_AS    __attribute__((address_space(3)))

__device__ __forceinline__ u8 to_fp8(float v) {
    __hip_fp8_e4m3 t(v);
    return *reinterpret_cast<u8*>(&t);
}

// k-permutation within 128-element chunks (8-elem granules), designed so the
// r17-proven CONFLICT-FREE read pattern (two 16B ds_read_b128 at offsets
// (kk2*64 + lq*16) ^ xr, kk2 in {0,1}) delivers the scaled-MFMA operand order
// k = lq*32 + kk2*16 + 0..15.  Granule g -> slot s (bit shuffle, bijective):
//   s(g) = ((g&2)<<2) | ((g&12)>>1) | (g&1)
// Trace: lq,kk2 -> slots {2lq+8kk2, 2lq+8kk2+1} -> granules -> k block. All 8
// cases verified: (0,0)->k0..15 (1,0)->32..47 (2,0)->64..79 (3,0)->96..111
// (0,1)->16..31 (1,1)->48..63 (2,1)->80..95 (3,1)->112..127.
__device__ __forceinline__ int perm8(int g) {
    return ((g & 2) << 2) | ((g & 12) >> 1) | (g & 1);
}
__device__ __forceinline__ int permk(int k) {   // full k-index permutation
    return (k & ~127) | (perm8((k >> 3) & 15) * 8 + (k & 7));
}

__device__ __forceinline__ float2 cadd(float2 a, float2 b){ return make_float2(a.x+b.x, a.y+b.y); }
__device__ __forceinline__ float2 csub(float2 a, float2 b){ return make_float2(a.x-b.x, a.y-b.y); }
__device__ __forceinline__ float2 cmul(float2 a, float2 b){ return make_float2(a.x*b.x-a.y*b.y, a.x*b.y+a.y*b.x); }
__device__ __forceinline__ float2 cmuli(float2 a){ return make_float2(-a.y, a.x); } // *(+i)

// inverse 8-point DFT (positive exponent), natural order
__device__ __forceinline__ void radix8_inv(const float2 v[8], float2 X[8]) {
    const float cc = 0.70710678118654752f;
    float2 a0 = cadd(v[0], v[4]), a1 = cadd(v[1], v[5]), a2 = cadd(v[2], v[6]), a3 = cadd(v[3], v[7]);
    float2 b0 = csub(v[0], v[4]), b1 = csub(v[1], v[5]), b2 = csub(v[2], v[6]), b3 = csub(v[3], v[7]);
    b1 = cmul(b1, make_float2(cc, cc));
    b2 = cmuli(b2);
    b3 = cmul(b3, make_float2(-cc, cc));
    float2 c0 = cadd(a0, a2), c1 = cadd(a1, a3), d0 = csub(a0, a2), d1 = cmuli(csub(a1, a3));
    float2 e0 = cadd(b0, b2), e1 = cadd(b1, b3), f0 = csub(b0, b2), f1 = cmuli(csub(b1, b3));
    X[0] = cadd(c0, c1); X[4] = csub(c0, c1); X[2] = cadd(d0, d1); X[6] = csub(d0, d1);
    X[1] = cadd(e0, e1); X[5] = csub(e0, e1); X[3] = cadd(f0, f1); X[7] = csub(f0, f1);
}

// ---------------- zero / scatter (transposed spectrum layout) ----------------

__global__ __launch_bounds__(256) void zero2_kernel(float2* p, int n) {
    int i = blockIdx.x*256 + threadIdx.x;
    if (i < n) p[i] = make_float2(0.f, 0.f);
}

__global__ __launch_bounds__(256) void scatter2_kernel(const float* __restrict__ crA,
                                                       const float* __restrict__ ciA,
                                                       const int* __restrict__ idxA,
                                                       const float* __restrict__ crB,
                                                       const float* __restrict__ ciB,
                                                       const int* __restrict__ idxB,
                                                       float2* __restrict__ specA,
                                                       float2* __restrict__ specB, int keep) {
    int i = blockIdx.x*256 + threadIdx.x;
    if (i < keep) {
        int k = idxA[i];
        long pos = (k < M_HALF) ? ((long)(k & 511)*4096 + (k >> 9)) : (long)M_HALF;
        specA[pos] = make_float2(crA[i], ciA[i]);
    } else if (i < 2*keep) {
        int t = i - keep;
        int k = idxB[t];
        long pos = (k < M_HALF) ? ((long)(k & 511)*4096 + (k >> 9)) : (long)M_HALF;
        specB[pos] = make_float2(crB[t], ciB[t]);
    }
}

// ---------------- pass 1: radix-4096 in-block (8 x 512-sub), prep fused -----

__global__ __launch_bounds__(512) void ifft_p4096_dual(const float2* __restrict__ specTA,
                                                       const float2* __restrict__ specTB,
                                                       float2* __restrict__ dstA,
                                                       float2* __restrict__ dstB,
                                                       const float* __restrict__ scaleA,
                                                       const float* __restrict__ scaleB) {
    __shared__ float2 L[8*656];
    int bb = blockIdx.x;
    const float2* spec; float2* dst; const float* scale;
    if (bb < 512) { spec = specTA; dst = dstA; scale = scaleA; }
    else          { bb -= 512; spec = specTB; dst = dstB; scale = scaleB; }
    const int j = bb;
    const int x = threadIdx.x;       // [0,512)
    const float s = scale[0] * (1.0f/(float)M_HALF);
    float2 v[8];
    {   // prep: angle pi*k/2^21, k = j + 512*(x+512u); step over u = pi/8
        float ang0 = (float)(3.14159265358979323846 * (double)(j + 512*x) / 2097152.0);
        float sn, cs; sincosf(ang0, &sn, &cs);
        const float2 step = make_float2(0.98078528040323044913f,
                                        0.19509032201612826785f);
        float2 tw = make_float2(cs, sn);
        const long arow = (long)j * 4096;
        const long brow = (long)(512 - j) * 4096;
#pragma unroll
        for (int u = 0; u < 8; ++u) {
            int t = x + 512*u;
            float2 a = spec[arow + t];
            float2 b;
            if (j == 0) b = (t == 0) ? spec[(long)M_HALF] : spec[4096 - t];
            else        b = spec[brow + 4095 - t];
            if (j == 0 && t == 0) { a.y = 0.0f; b.y = 0.0f; }
            float Er = 0.5f*(a.x + b.x), Ei = 0.5f*(a.y - b.y);
            float Tr = 0.5f*(a.x - b.x), Ti = 0.5f*(a.y + b.y);
            float Or = Tr*tw.x - Ti*tw.y, Oi = Tr*tw.y + Ti*tw.x;
            v[u] = make_float2((Er - Oi)*s, (Ei + Or)*s);
            tw = cmul(tw, step);
        }
    }
    float2 E[8];
    radix8_inv(v, E);
    {   // twiddle cis(2pi a x / 4096)
        float cb, sb; sincosf((float)x * 0.0015339807878856412f, &sb, &cb);
        float2 wb = make_float2(cb, sb), w = make_float2(1.f, 0.f);
#pragma unroll
        for (int a = 0; a < 8; ++a) { L[a*656 + x] = cmul(E[a], w); w = cmul(w, wb); }
    }
    __syncthreads();
    const int g = x >> 6, xin = x & 63;
    float2* Lg = L + g*656;
    float2 v2[8];
#pragma unroll
    for (int u2 = 0; u2 < 8; ++u2) v2[u2] = Lg[xin + 64*u2];
    float2 E2[8];
    radix8_inv(v2, E2);
    __syncthreads();
    {   // T1 = cis(2pi s8 xin/512)
        float cb, sb; sincosf((float)xin * 0.012271846303085130f, &sb, &cb);
        float2 wb = make_float2(cb, sb), w = make_float2(1.f, 0.f);
#pragma unroll
        for (int s8 = 0; s8 < 8; ++s8) { Lg[s8*65 + xin] = cmul(E2[s8], w); w = cmul(w, wb); }
    }
    __syncthreads();
    const int p = xin >> 3, xa = xin & 7;
    float2 g2[8];
#pragma unroll
    for (int xb = 0; xb < 8; ++xb) g2[xb] = Lg[p*65 + xa + 8*xb];
    float2 H2[8];
    radix8_inv(g2, H2);
    __syncthreads();
    {   // T2 = cis(2pi o8 xa/64)
        float cb, sb; sincosf((float)xa * 0.098174770424681039f, &sb, &cb);
        float2 wb = make_float2(cb, sb), w = make_float2(1.f, 0.f);
#pragma unroll
        for (int o8 = 0; o8 < 8; ++o8) { Lg[p*81 + o8*9 + xa] = cmul(H2[o8], w); w = cmul(w, wb); }
    }
    __syncthreads();
    const int pp = xin & 7, sp = xin >> 3;
    float2 r2[8];
#pragma unroll
    for (int xa2 = 0; xa2 < 8; ++xa2) r2[xa2] = Lg[pp*81 + sp*9 + xa2];
    float2 D[8];
    radix8_inv(r2, D);               // s = g + 8*xin + 512*ob
    __syncthreads();
#pragma unroll
    for (int ob = 0; ob < 8; ++ob) {
        int sg = g + 8*xin + 512*ob;
        L[sg ^ ((sg >> 4) & 7)] = D[ob];
    }
    __syncthreads();
    const long obase = (long)j * 4096;
#pragma unroll
    for (int e = 0; e < 8; ++e) {
        int idx = x + 512*e;
        dst[obase + idx] = L[idx ^ ((idx >> 4) & 7)];
    }
}

// ---------------- pass 2 (FINAL): radix-512, outer twiddle, fp8(x256) out ---
// n = jg + s*4096 indexes complex pairs; w element e = 2n, row r = e/C (the
// GEMM k-dim). Store with ROW k-permutation: n' = permk(r)*(C/2) + (col pair).
// Weight A: C=4096; weight B: C=1024.

__global__ __launch_bounds__(512) void ifft_p512f8_dual(const float2* __restrict__ srcA,
                                                        u8* __restrict__ dstwA,
                                                        const float2* __restrict__ srcB,
                                                        u8* __restrict__ dstwB) {
    __shared__ float2 ex[8 * 642];
    int bb = blockIdx.x;
    const float2* src; u8* dstw; bool isA;
    if (bb < 512) { src = srcA; dstw = dstwA; isA = true; }
    else          { bb -= 512; src = srcB; dstw = dstwB; isA = false; }
    const int tid = threadIdx.x;
    const int jl = tid & 7, x = tid >> 3;    // x in [0,64)
    const int jg = bb * 8 + jl;              // [0,4096)
    float2* W = ex + jl * 642;
    float2 v[8];
    {   // outer twiddle cis(2pi jg (x+64u)/2^21)
        float a0 = (float)(6.283185307179586 * (double)jg * (double)x / 2097152.0);
        float sn0, cs0; sincosf(a0, &sn0, &cs0);
        float as = (float)(6.283185307179586 * (double)jg / 32768.0);
        float sns, css; sincosf(as, &sns, &css);
        float2 tw = make_float2(cs0, sn0), stepw = make_float2(css, sns);
#pragma unroll
        for (int u = 0; u < 8; ++u) {
            v[u] = cmul(src[jg + (long)(x + 64*u) * 4096], tw);
            tw = cmul(tw, stepw);
        }
    }
    float2 E[8];
    radix8_inv(v, E);
    {   // T1 = cis(2pi s8 x / 512)
        float cb, sb; sincosf((float)x * 0.012271846303085130f, &sb, &cb);
        float2 wb = make_float2(cb, sb), w = make_float2(1.f, 0.f);
#pragma unroll
        for (int s8 = 0; s8 < 8; ++s8) {
            W[s8*65 + x] = cmul(E[s8], w);
            w = cmul(w, wb);
        }
    }
    __syncthreads();
    const int p = x >> 3, xa = x & 7;
    float2 g[8];
#pragma unroll
    for (int xb = 0; xb < 8; ++xb) g[xb] = W[p*65 + xa + 8*xb];
    float2 H[8];
    radix8_inv(g, H);
    __syncthreads();
    {   // T2 = cis(2pi o8 xa / 64)
        float cb, sb; sincosf((float)xa * 0.098174770424681039f, &sb, &cb);
        float2 wb = make_float2(cb, sb), w = make_float2(1.f, 0.f);
#pragma unroll
        for (int o8 = 0; o8 < 8; ++o8) {
            W[p*81 + o8*9 + xa] = cmul(H[o8], w);
            w = cmul(w, wb);
        }
    }
    __syncthreads();
    const int pp = x & 7, sp = x >> 3;
    float2 r[8];
#pragma unroll
    for (int xa2 = 0; xa2 < 8; ++xa2) r[xa2] = W[pp*81 + sp*9 + xa2];
    float2 Y[8];
    radix8_inv(r, Y);                // s = x + 64*ob
#pragma unroll
    for (int ob = 0; ob < 8; ++ob) {
        int sidx = x + 64*ob;
        long n2;
        if (isA) {                    // C=4096: r = 2s + (jg>>11), colpair = jg&2047
            int rr = 2*sidx + (jg >> 11);
            n2 = (long)permk(rr) * 2048 + (jg & 2047);
        } else {                      // C=1024: r = 8s + (jg>>9), colpair = jg&511
            int rr = 8*sidx + (jg >> 9);
            n2 = (long)permk(rr) * 512 + (jg & 511);
        }
        unsigned short pk = (unsigned short)to_fp8(Y[ob].x * W_SCALE) |
                            ((unsigned short)to_fp8(Y[ob].y * W_SCALE) << 8);
        ((unsigned short*)dstw)[n2] = pk;
    }
}

// ---------------- transpose fp8, dual-weight (w[R][C] -> wT[C][R]) ----------
// Row permutation already applied by p512f8; transpose passes it through to
// the fast (k) dim of wT.

__global__ __launch_bounds__(256) void transpose_f8_dual(const u8* __restrict__ wA,
                                                         u8* __restrict__ wTA,
                                                         const u8* __restrict__ wB,
                                                         u8* __restrict__ wTB) {
    __shared__ u8 tile[32][36];
    int b = blockIdx.x;
    const u8* w; u8* wT; int R, C, bx, by;
    if (b < 4096) { w = wA; wT = wTA; R = 1024; C = 4096; bx = b & 127; by = b >> 7; }
    else { b -= 4096; w = wB; wT = wTB; R = 4096; C = 1024; bx = b & 31; by = b >> 5; }
    int tx = threadIdx.x & 31, ty = threadIdx.x >> 5;
    long c0 = (long)bx * 32, r0 = (long)by * 32;
#pragma unroll
    for (int i = 0; i < 4; ++i)
        tile[ty + i*8][tx] = w[(r0 + ty + i*8) * C + c0 + tx];
    __syncthreads();
#pragma unroll
    for (int i = 0; i < 4; ++i) {
        int c = ty + i*8;
        wT[(c0 + c) * R + r0 + tx] = tile[tx][c];
    }
}

// ---------------- fp32 -> fp8 convert (x), k-permuted output ----------------
// One 8-elem granule per thread: fully coalesced 128B chunks, permuted slots.

__global__ __launch_bounds__(256) void cvt_fp8_kernel(const float* __restrict__ in,
                                                      u8* __restrict__ out, int n8) {
    int i = blockIdx.x*256 + threadIdx.x;
    if (i < n8) {
        float4 v0 = ((const float4*)in)[i*2];
        float4 v1 = ((const float4*)in)[i*2+1];
        unsigned long pk =  (unsigned long)to_fp8(v0.x)
                         | ((unsigned long)to_fp8(v0.y) << 8)
                         | ((unsigned long)to_fp8(v0.z) << 16)
                         | ((unsigned long)to_fp8(v0.w) << 24)
                         | ((unsigned long)to_fp8(v1.x) << 32)
                         | ((unsigned long)to_fp8(v1.y) << 40)
                         | ((unsigned long)to_fp8(v1.z) << 48)
                         | ((unsigned long)to_fp8(v1.w) << 56);
        ((unsigned long*)out)[(i >> 4) * 16 + perm8(i & 15)] = pk;
    }
}

// ---------------- staging helper (byte-based, swizzled) ----------------
// LDS[row][gb] = G[row][gb ^ (row&7)] on 16B granules within 128B rows:
// pre-swizzled global source -> linear global_load_lds dest; reads XOR back.

template<int NITER>
__device__ __forceinline__ void stage_b(const u8* g, int ldB, int row0, int col0B,
                                        u8* lds, int tid) {
    int w = tid >> 6, l = tid & 63;        // w in [0,8)
    int r8 = l >> 3;
    int cg = ((l & 7) ^ r8) << 4;          // pre-swizzled byte col (16B granule)
#pragma unroll
    for (int i = 0; i < NITER; ++i) {
        int chunk = (i << 3) + w;          // NITER*8 chunks x 8 rows x 128 B
        const u8* ga = g + (long)(row0 + chunk*8 + r8) * ldB + col0B + cg;
        u8* la = lds + (chunk << 10);
        __builtin_amdgcn_global_load_lds((const GLOBAL_AS unsigned int*)ga,
                                         (LDS_AS unsigned int*)la, 16, 0, 0);
    }
}

// ---------------- 128x128-tile GEMM, 8 waves, MX-scaled fp8 K=128 ------------
// Scaled MFMA (2x fp8 rate), e8m0 scales = 1.0 -> numerically plain fp8.
// Fragment loads use r17's EMPIRICALLY CONFLICT-FREE byte pattern: two
// ds_read_b128 per 32B operand at offsets (kk2*64 + lq*16) ^ xr (distance 64,
// unmergeable); the k-permuted storage (perm8 above) makes those bytes be
// exactly k = lq*32 + kk2*16 + 0..15. r18/r19's distance-16 pattern measured
// 4 conflict-cycles per read; this one measured 0 in r17.
// EPI=0: bias+gelu -> fp8 h (k-permuted cols); EPI=1: bias -> fp32 out.

template<int EPI>
__global__ __launch_bounds__(512, 6) void gemm_f8(const u8* __restrict__ A,
                                                  const u8* __restrict__ Bt,
                                                  const float* __restrict__ bias,
                                                  void* __restrict__ Cout,
                                                  int M, int N, int K,
                                                  int CR, int CC, int GXC) {
    __shared__ __align__(16) u8 lA[128*128];
    __shared__ __align__(16) u8 lB[128*128];
    const int tid = threadIdx.x;
    const int l = tid & 63, w = tid >> 6;
    const int wr = w >> 2, wc = w & 3;
    // XCD-chunked swizzle (bijective; grid multiple of 8)
    int flat = blockIdx.y * gridDim.x + blockIdx.x;
    int r = flat & 7, q = flat >> 3;
    int ty = (r / GXC) * CR + q / CC;
    int tx = (r % GXC) * CC + q % CC;
    const int row0 = ty * 128, col0 = tx * 128;
    const int lr = l & 15, lq = l >> 4;
    const int xr = (lr & 7) << 4;
    const int kb0 = (lq*16) ^ xr;          // k = lq*32 + 0..15  (permuted layout)
    const int kb1 = (64 + lq*16) ^ xr;     // k = lq*32 + 16..31
    f32x4 acc[4][2] = {};
    for (int k0 = 0; k0 < K; k0 += 128) {
        stage_b<2>(A,  K, row0, k0, lA, tid);
        stage_b<2>(Bt, K, col0, k0, lB, tid);
        __syncthreads();
        i32x8 bfr[2];
#pragma unroll
        for (int ni = 0; ni < 2; ++ni) {
            const u8* rp = lB + (wc*32 + ni*16 + lr)*128;
            i32x4 lo = *(const i32x4*)(rp + kb0);
            i32x4 hi = *(const i32x4*)(rp + kb1);
            bfr[ni] = __builtin_shufflevector(lo, hi, 0, 1, 2, 3, 4, 5, 6, 7);
        }
#pragma unroll
        for (int mh = 0; mh < 2; ++mh) {   // mi in {2mh, 2mh+1}: bounds live regs
            i32x8 af[2];
#pragma unroll
            for (int m2 = 0; m2 < 2; ++m2) {
                const u8* rp = lA + (wr*64 + (mh*2 + m2)*16 + lr)*128;
                i32x4 lo = *(const i32x4*)(rp + kb0);
                i32x4 hi = *(const i32x4*)(rp + kb1);
                af[m2] = __builtin_shufflevector(lo, hi, 0, 1, 2, 3, 4, 5, 6, 7);
            }
#pragma unroll
            for (int m2 = 0; m2 < 2; ++m2)
#pragma unroll
                for (int ni = 0; ni < 2; ++ni)
                    acc[mh*2 + m2][ni] = __builtin_amdgcn_mfma_scale_f32_16x16x128_f8f6f4(
                        af[m2], bfr[ni], acc[mh*2 + m2][ni],
                        0, 0,                      // cbsz=fp8, blgp=fp8
                        0, 0x7F7F7F7F,             // scale_a opsel, e8m0 1.0
                        0, 0x7F7F7F7F);            // scale_b opsel, e8m0 1.0
        }
        __syncthreads();
    }
    const float inv_s = 1.0f / W_SCALE;
#pragma unroll
    for (int mi = 0; mi < 4; ++mi) {
#pragma unroll
        for (int ni = 0; ni < 2; ++ni) {
            int c = col0 + wc*32 + ni*16 + lr;
            float bv = bias[c];
#pragma unroll
            for (int q2 = 0; q2 < 4; ++q2) {
                int rr = row0 + wr*64 + mi*16 + lq*4 + q2;
                float v = acc[mi][ni][q2] * inv_s + bv;
                if constexpr (EPI == 0) {
                    float y = -1.5957691216057308f * (v + 0.044715f * v * v * v);
                    v = v / (1.0f + __expf(y));
                    ((u8*)Cout)[(long)rr * N + permk(c)] = to_fp8(v);
                } else {
                    ((float*)Cout)[(long)rr * N + c] = v;
                }
            }
        }
    }
}

// ---------------- launch ----------------

extern "C" void kernel_launch(void* const* d_in, const int* in_sizes, int n_in,
                              void* d_out, int out_size, void* d_ws, size_t ws_size,
                              hipStream_t stream) {
    const float* x        = (const float*)d_in[0];
    const float* fc_cr    = (const float*)d_in[1];
    const float* fc_ci    = (const float*)d_in[2];
    const int*   fc_idx   = (const int*)  d_in[3];
    const float* fc_scale = (const float*)d_in[4];
    const float* fc_bias  = (const float*)d_in[5];
    const float* pj_cr    = (const float*)d_in[6];
    const float* pj_ci    = (const float*)d_in[7];
    const int*   pj_idx   = (const int*)  d_in[8];
    const float* pj_scale = (const float*)d_in[9];
    const float* pj_bias  = (const float*)d_in[10];
    const int keep = in_sizes[1];

    char* ws = (char*)d_ws;
    // Persistent: wT fp8 [0,8), x fp8 [8,16), h fp8 [16,48)
    u8* w_fcT = (u8*)(ws + 0);                  // 4 MiB [4096][1024]
    u8* w_pjT = (u8*)(ws + 4194304);            // 4 MiB [1024][4096]
    u8* x_f8  = (u8*)(ws + 8388608);            // 8 MiB [8192][1024] (written after FFT)
    u8* h_f8  = (u8*)(ws + 16777216);           // 32 MiB [8192][4096] (GEMM1 out)
    // FFT scratch, time-sliced:
    const long SP = (long)M_HALF + 64;
    float2* specA = (float2*)(ws + 8388608);    // [8, ~42): dies after p4096
    float2* specB = specA + SP;
    float2* fftA_A = (float2*)(ws + 50331648);  // [48,64): dies after p512f8
    float2* fftA_B = (float2*)(ws + 67108864);  // [64,80)
    u8* w_natA = (u8*)(ws + 8388608);           // [8,12) over dead spec
    u8* w_natB = (u8*)(ws + 12582912);          // [12,16)

    // --- FFT chain, 2 passes, both weights batched ---
    zero2_kernel<<<(int)((2*SP + 255)/256), 256, 0, stream>>>(specA, (int)(2*SP));
    scatter2_kernel<<<(2*keep + 255)/256, 256, 0, stream>>>(
        fc_cr, fc_ci, fc_idx, pj_cr, pj_ci, pj_idx, specA, specB, keep);
    ifft_p4096_dual<<<1024, 512, 0, stream>>>(specA, specB, fftA_A, fftA_B,
                                              fc_scale, pj_scale);
    ifft_p512f8_dual<<<1024, 512, 0, stream>>>(fftA_A, w_natA, fftA_B, w_natB);
    transpose_f8_dual<<<8192, 256, 0, stream>>>(w_natA, w_fcT, w_natB, w_pjT);

    // --- x -> fp8, k-permuted (clobbers dead w_nat region, after transpose) ---
    cvt_fp8_kernel<<<8388608/8/256, 256, 0, stream>>>(x, x_f8, 8388608/8);

    // GEMM1: 128^2 tiles, grid = 32 x 64 = 2048; XCD chunks 16x16 (GXC=2)
    gemm_f8<0><<<dim3(4096/128, 8192/128), 512, 0, stream>>>(
        x_f8, w_fcT, fc_bias, h_f8, 8192, 4096, 1024, 16, 16, 2);

    // GEMM2: 128^2 tiles, grid = 8 x 64 = 512; XCD chunks 8x8 (GXC=1)
    gemm_f8<1><<<dim3(1024/128, 8192/128), 512, 0, stream>>>(
        h_f8, w_pjT, pj_bias, d_out, 8192, 1024, 4096, 8, 8, 1);

    (void)n_in; (void)out_size; (void)ws_size;
}